// Round 4
// baseline (587.361 us; speedup 1.0000x reference)
//
#include <hip/hip_runtime.h>
#include <hip/hip_bf16.h>

#define TOKENS 8192
#define DMODEL 1024
#define NEXP   8
#define DFF    4096
#define CAP    1280

typedef short bf16x8_t __attribute__((ext_vector_type(8)));
typedef float f32x4_t  __attribute__((ext_vector_type(4)));

__device__ __forceinline__ float bf2f(ushort u) {
    union { unsigned int i; float f; } v; v.i = ((unsigned int)u) << 16; return v.f;
}
__device__ __forceinline__ ushort f2bf(float f) {
    union { float f; unsigned int i; } v; v.f = f;
    unsigned int r = v.i + 0x7fffu + ((v.i >> 16) & 1u);   // RNE
    return (ushort)(r >> 16);
}
// async global->LDS DMA, 16B per lane, dest = uniform base + lane*16
__device__ __forceinline__ void load_lds16(const void* g, void* l) {
    __builtin_amdgcn_global_load_lds(
        (const __attribute__((address_space(1))) void*)g,
        (__attribute__((address_space(3))) void*)l, 16, 0, 0);
}

// ---------------------------------------------------------------- gate ------
__global__ __launch_bounds__(256) void gate_kernel(
    const float* __restrict__ tokens, const float* __restrict__ gw,
    int* __restrict__ eidx, float* __restrict__ prob)
{
    int lane = threadIdx.x & 63;
    int wave = threadIdx.x >> 6;
    int t = blockIdx.x * 4 + wave;
    const float* tok = tokens + (long)t * DMODEL;
    float s[NEXP] = {0.f,0.f,0.f,0.f,0.f,0.f,0.f,0.f};
    #pragma unroll
    for (int c = 0; c < 4; c++) {
        int d = c * 256 + lane * 4;
        float4 x = *(const float4*)(tok + d);
        #pragma unroll
        for (int e = 0; e < NEXP; e++) {
            float4 g = *(const float4*)(gw + e * DMODEL + d);
            s[e] += x.x*g.x + x.y*g.y + x.z*g.z + x.w*g.w;
        }
    }
    #pragma unroll
    for (int e = 0; e < NEXP; e++) {
        #pragma unroll
        for (int off = 32; off > 0; off >>= 1) s[e] += __shfl_xor(s[e], off);
    }
    if (lane == 0) {
        float m = s[0]; int am = 0;
        #pragma unroll
        for (int e = 1; e < NEXP; e++) if (s[e] > m) { m = s[e]; am = e; }
        float sum = 0.f;
        #pragma unroll
        for (int e = 0; e < NEXP; e++) sum += expf(s[e] - m);
        eidx[t] = am;
        prob[t] = 1.0f / sum;
    }
}

// ------------------------------------------------------------- routing ------
__global__ __launch_bounds__(1024) void route_scan(
    const int* __restrict__ eidx, int* __restrict__ pos, int* __restrict__ cnt)
{
    __shared__ unsigned long long pa[16], pb[16];
    int tid = threadIdx.x;
    int lane = tid & 63, wid = tid >> 6;
    int4 e0 = *(const int4*)(eidx + tid * 8);
    int4 e1 = *(const int4*)(eidx + tid * 8 + 4);
    int le[8] = {e0.x, e0.y, e0.z, e0.w, e1.x, e1.y, e1.z, e1.w};
    unsigned long long ha = 0, hb = 0;
    #pragma unroll
    for (int i = 0; i < 8; i++) {
        int e = le[i];
        if (e < 4) ha += 1ull << (e * 16);
        else       hb += 1ull << ((e - 4) * 16);
    }
    unsigned long long ia = ha, ib = hb;       // inclusive scan within wave
    #pragma unroll
    for (int off = 1; off < 64; off <<= 1) {
        unsigned long long ua = __shfl_up(ia, off);
        unsigned long long ub = __shfl_up(ib, off);
        if (lane >= off) { ia += ua; ib += ub; }
    }
    if (lane == 63) { pa[wid] = ia; pb[wid] = ib; }   // wave totals
    __syncthreads();
    if (tid < 64) {   // wave 0 scans the 16 wave totals -> exclusive bases
        unsigned long long va = (lane < 16) ? pa[lane] : 0;
        unsigned long long vb = (lane < 16) ? pb[lane] : 0;
        unsigned long long oa = va, ob = vb;
        #pragma unroll
        for (int off = 1; off < 16; off <<= 1) {
            unsigned long long ua = __shfl_up(va, off);
            unsigned long long ub = __shfl_up(vb, off);
            if (lane >= off) { va += ua; vb += ub; }
        }
        if (lane < 16) { pa[lane] = va - oa; pb[lane] = vb - ob; }
        if (lane == 15) {   // inclusive over all 16 waves = per-expert totals
            #pragma unroll
            for (int e = 0; e < 4; e++) {
                cnt[e]     = (int)((va >> (e * 16)) & 0xffffu);
                cnt[e + 4] = (int)((vb >> (e * 16)) & 0xffffu);
            }
        }
    }
    __syncthreads();
    unsigned long long ba = pa[wid] + (ia - ha);   // exclusive per-thread base
    unsigned long long bb = pb[wid] + (ib - hb);
    int po[8];
    #pragma unroll
    for (int i = 0; i < 8; i++) {
        int e = le[i];
        if (e < 4) { int sh = e * 16;       po[i] = (int)((ba >> sh) & 0xffffu); ba += 1ull << sh; }
        else       { int sh = (e - 4) * 16; po[i] = (int)((bb >> sh) & 0xffffu); bb += 1ull << sh; }
    }
    *(int4*)(pos + tid * 8)     = (int4){po[0], po[1], po[2], po[3]};
    *(int4*)(pos + tid * 8 + 4) = (int4){po[4], po[5], po[6], po[7]};
}

// ------------------------------------------------------------ dispatch ------
__global__ __launch_bounds__(256) void dispatch_gather(
    const float* __restrict__ tokens, const int* __restrict__ eidx,
    const int* __restrict__ pos, ushort* __restrict__ disp)
{
    int t = blockIdx.x;
    int p = pos[t];
    if (p >= CAP) return;
    int e = eidx[t];
    int d = threadIdx.x * 4;
    float4 v = *(const float4*)(tokens + (long)t * DMODEL + d);
    union { uint2 u; ushort h[4]; } o;
    o.h[0] = f2bf(v.x); o.h[1] = f2bf(v.y); o.h[2] = f2bf(v.z); o.h[3] = f2bf(v.w);
    *(uint2*)(disp + ((long)e * CAP + p) * DMODEL + d) = o.u;
}

// ----------------------------------------------------------- transpose ------
__global__ __launch_bounds__(256) void transpose_f32_bf16(
    const float* __restrict__ in, ushort* __restrict__ out, int R, int C)
{
    __shared__ ushort tile[64 * 64];
    long base = (long)blockIdx.z * R * C;
    int r0 = blockIdx.y * 64, c0 = blockIdx.x * 64;
    int tid = threadIdx.x;
    int rr = tid >> 4;            // 0..15
    int cf = (tid & 15) * 4;      // float4 col
    const float* ip = in + base + (long)(r0 + rr) * C + c0 + cf;
    #pragma unroll
    for (int q = 0; q < 4; q++) {
        int r = rr + q * 16;
        float4 v = *(const float4*)(ip + (long)q * 16 * C);
        int rlo = r & 7, rhi = r >> 3;
        tile[(cf+0) * 64 + ((rhi ^ ((cf+0) & 7)) << 3) + rlo] = f2bf(v.x);
        tile[(cf+1) * 64 + ((rhi ^ ((cf+1) & 7)) << 3) + rlo] = f2bf(v.y);
        tile[(cf+2) * 64 + ((rhi ^ ((cf+2) & 7)) << 3) + rlo] = f2bf(v.z);
        tile[(cf+3) * 64 + ((rhi ^ ((cf+3) & 7)) << 3) + rlo] = f2bf(v.w);
    }
    __syncthreads();
    int oc = tid >> 3;            // 0..31
    int j  = tid & 7;             // 16B chunk within out row
    #pragma unroll
    for (int q = 0; q < 2; q++) {
        int c = oc + q * 32;
        uint4 w = *(const uint4*)&tile[c * 64 + ((j ^ (c & 7)) << 3)];
        *(uint4*)(out + base + (long)(c0 + c) * R + r0 + j * 8) = w;
    }
}

// --------------------------------------------------- GEMM1: 256^2 8-phase ---
// m201-template reconstruction with K-split LDS halves.
//  - 256x256 tile, BK=64, 512 thr (8 waves 2Mx4N), per-wave C = 128x64.
//  - LDS: per matrix a 4-slot ring, slot = [256 rows][32 k] bf16 (16 KB).
//    Slot of (tile t, khalf h) = (2t+h)&3.  A+B = 128 KiB.
//  - 4 phases per K-tile: ph(ch,kh) = (0,0),(1,0),(0,1),(1,1):
//      {ds_read 4 A-frags (+4 B-frags when ch==0); stage ONE half-tile
//       (2 global_load_lds); s_barrier; setprio(1); 16 MFMA; setprio(0);
//       [vmcnt(6) at ph3 only]; s_barrier}
//  - Stage schedule (slot freed exactly one phase earlier, reads provably
//    complete since ds_reads drain via lgkm before the MFMA cluster):
//      ph0: A(t+1,k1)  ph1: B(t+2,k0)  ph2: A(t+2,k0)  ph3: B(t+2,k1)
//    vmcnt(6) at ph3 leaves exactly 3 half-tiles in flight and retires
//    through A(t+1,k1) -> tile t+1 fully landed.  Last 2 tiles: vmcnt(0).
//  - Bank swizzle: phys chunk = q ^ ((row>>1)&3) (2 lanes/16B-slot = free);
//    applied on the global source side (DMA dest stays linear, m104).
//  - Capacity skip via cnt[] as in gemm_bt.
__global__ __launch_bounds__(512, 2) void gemm1_8ph(
    const ushort* __restrict__ A, const ushort* __restrict__ B,
    const float* __restrict__ bias, ushort* __restrict__ C,
    const int* __restrict__ cnt,
    int N, int K, int do_relu,
    long sA, long sB, long sBias, long sC)
{
    __shared__ ushort As[4 * 8192];   // 64 KB
    __shared__ ushort Bs[4 * 8192];   // 64 KB

    // XCD-aware swizzle (nwg = 16*5*8 = 640, %8 == 0)
    int gx = gridDim.x, gy = gridDim.y;
    int nwg = gx * gy * gridDim.z;
    int lin = blockIdx.x + gx * (blockIdx.y + gy * blockIdx.z);
    int cpx = nwg >> 3;
    int swz = (lin & 7) * cpx + (lin >> 3);
    int bz  = swz / (gx * gy);
    int rem = swz - bz * gx * gy;
    int by  = rem / gx, bx = rem - by * gx;

    if (by * 256 >= cnt[bz]) return;   // capacity slack

    A += bz * sA; B += bz * sB; bias += bz * sBias; C += bz * sC;
    long m0 = (long)by * 256, n0 = (long)bx * 256;

    int tid  = threadIdx.x;
    int lane = tid & 63, wave = tid >> 6;
    int wm = (wave >> 2) * 128;     // 2 M-groups of 128 rows
    int wn = (wave & 3) * 64;       // 4 N-groups of 64 cols
    int fm = lane & 15;             // fragment row/col within 16
    int q  = lane >> 4;             // 0..3 (k-quad within 32-k half)
    int rxk = (q ^ ((fm >> 1) & 3)) * 8;   // swizzled chunk offset (ushorts)

    // staging source bases: call0 covers rows 0..127, call1 rows 128..255
    int tr0 = tid >> 2, tr1 = tr0 + 128;
    int pc  = tid & 3;
    int lc0 = pc ^ ((tr0 >> 1) & 3);
    int lc1 = pc ^ ((tr1 >> 1) & 3);
    const ushort* AgS0 = A + (long)(m0 + tr0) * K + lc0 * 8;
    const ushort* AgS1 = A + (long)(m0 + tr1) * K + lc1 * 8;
    const ushort* BgS0 = B + (long)(n0 + tr0) * K + lc0 * 8;
    const ushort* BgS1 = B + (long)(n0 + tr1) * K + lc1 * 8;
    int wb = wave * 512;            // wave-uniform dest offset within call

#define STAGE_A(s, ko) do { \
    load_lds16(AgS0 + (ko), &As[(s) * 8192 + wb]); \
    load_lds16(AgS1 + (ko), &As[(s) * 8192 + 4096 + wb]); } while (0)
#define STAGE_B(s, ko) do { \
    load_lds16(BgS0 + (ko), &Bs[(s) * 8192 + wb]); \
    load_lds16(BgS1 + (ko), &Bs[(s) * 8192 + 4096 + wb]); } while (0)

    f32x4_t acc[8][4];
    #pragma unroll
    for (int i = 0; i < 8; i++)
        #pragma unroll
        for (int j = 0; j < 4; j++) acc[i][j] = (f32x4_t){0.f,0.f,0.f,0.f};

    int KT = K >> 6;                // 16 for K=1024

    // ---- prologue: 7 half-tiles in consumption order; retire first 4
    STAGE_B(0, 0);  STAGE_A(0, 0);
    STAGE_B(1, 32); STAGE_A(1, 32);
    STAGE_B(2, 64); STAGE_A(2, 64);
    STAGE_B(3, 96);
    asm volatile("s_waitcnt vmcnt(6)" ::: "memory");
    __builtin_amdgcn_s_barrier();

    bf16x8_t bfr[4];
    for (int kt = 0; kt < KT; ++kt) {
        #pragma unroll
        for (int p = 0; p < 4; ++p) {
            const int ch = p & 1, kh = p >> 1;
            const int sl = ((kt << 1) + kh) & 3;
            const ushort* Asl = &As[sl * 8192];
            const ushort* Bsl = &Bs[sl * 8192];
            // ---- ds_reads (B once per khalf, A every phase)
            if (ch == 0) {
                #pragma unroll
                for (int j = 0; j < 4; j++) {
                    int r = wn + 16*j + fm;
                    bfr[j] = *(const bf16x8_t*)&Bsl[r * 32 + rxk];
                }
            }
            bf16x8_t af[4];
            #pragma unroll
            for (int i = 0; i < 4; i++) {
                int r = wm + ch*64 + 16*i + fm;
                af[i] = *(const bf16x8_t*)&Asl[r * 32 + rxk];
            }
            // ---- stage exactly one half-tile (slot freed one phase ago)
            if (p == 0)      { if (kt+1 < KT) STAGE_A((((kt+1)<<1)+1)&3, (kt+1)*64 + 32); }
            else if (p == 1) { if (kt+2 < KT) STAGE_B(( (kt+2)<<1     )&3, (kt+2)*64     ); }
            else if (p == 2) { if (kt+2 < KT) STAGE_A(( (kt+2)<<1     )&3, (kt+2)*64     ); }
            else             { if (kt+2 < KT) STAGE_B((((kt+2)<<1)+1)&3, (kt+2)*64 + 32); }
            __builtin_amdgcn_s_barrier();               // pre-MFMA align
            __builtin_amdgcn_s_setprio(1);
            #pragma unroll
            for (int i = 0; i < 4; i++)
                #pragma unroll
                for (int j = 0; j < 4; j++)
                    acc[ch*4 + i][j] = __builtin_amdgcn_mfma_f32_16x16x32_bf16(
                        af[i], bfr[j], acc[ch*4 + i][j], 0, 0, 0);
            __builtin_amdgcn_s_setprio(0);
            if (p == 3) {           // once per K-tile; next tile fully lands
                if (kt < KT - 2) asm volatile("s_waitcnt vmcnt(6)" ::: "memory");
                else             asm volatile("s_waitcnt vmcnt(0)" ::: "memory");
            }
            __builtin_amdgcn_s_barrier();               // phase end
        }
    }

    // epilogue: C/D layout col=lane&15, row=(lane>>4)*4+reg  [m89-verified]
    #pragma unroll
    for (int j = 0; j < 4; j++) {
        long col = n0 + wn + 16*j + fm;
        float bv = bias[col];
        #pragma unroll
        for (int i = 0; i < 8; i++) {
            long row = m0 + wm + 16*i + q * 4;
            #pragma unroll
            for (int r = 0; r < 4; r++) {
                float v = acc[i][j][r] + bv;
                if (do_relu) v = fmaxf(v, 0.f);
                C[(row + r) * N + col] = f2bf(v);
            }
        }
    }
#undef STAGE_A
#undef STAGE_B
}

// ------------------------------------------- GEMM2: proven 128^2 2-phase ----
__global__ __launch_bounds__(256) void gemm_bt(
    const ushort* __restrict__ A, const ushort* __restrict__ B,
    const float* __restrict__ bias, ushort* __restrict__ C,
    const int* __restrict__ cnt,
    int M, int N, int K, int do_relu,
    long sA, long sB, long sBias, long sC)
{
    if ((int)blockIdx.y * 128 >= cnt[blockIdx.z]) return;   // capacity slack

    A += blockIdx.z * sA; B += blockIdx.z * sB;
    bias += blockIdx.z * sBias; C += blockIdx.z * sC;

    __shared__ ushort As[128 * 64];   // 16 KB, unpadded (DMA layout)
    __shared__ ushort Bs[128 * 64];

    int tid  = threadIdx.x;
    int lane = tid & 63, wave = tid >> 6;
    int wm = (wave >> 1) * 64, wn = (wave & 1) * 64;
    int fm = lane & 15;             // fragment row/col within 16
    int q  = lane >> 4;             // 0..3  (k-quad)
    int rx = fm & 7;                // row&7 for swizzle on read side
    int m0 = blockIdx.y * 128, n0 = blockIdx.x * 128;

    // staging: lane i covers row (i>>3), swizzled chunk (i&7)^(i>>3)
    int srow = lane >> 3;                       // 0..7 within 8-row group
    int schk = (lane & 7) ^ srow;               // logical chunk to fetch
    const ushort* Ag = A + (long)(m0 + 32*wave + srow) * K + schk * 8;
    const ushort* Bg = B + (long)(n0 + 32*wave + srow) * K + schk * 8;
    ushort* AsW = &As[(32*wave) * 64];          // wave-uniform LDS bases
    ushort* BsW = &Bs[(32*wave) * 64];

    f32x4_t acc[4][4];
    #pragma unroll
    for (int i = 0; i < 4; i++)
        #pragma unroll
        for (int j = 0; j < 4; j++) acc[i][j] = (f32x4_t){0.f,0.f,0.f,0.f};

    for (int k0 = 0; k0 < K; k0 += 64) {
        #pragma unroll
        for (int t = 0; t < 4; t++) {
            load_lds16(Ag + (long)(8*t) * K + k0, AsW + (8*t) * 64);
            load_lds16(Bg + (long)(8*t) * K + k0, BsW + (8*t) * 64);
        }
        __syncthreads();   // compiler drains vmcnt before s_barrier
        #pragma unroll
        for (int kk = 0; kk < 64; kk += 32) {
            int l0 = (kk >> 3) + q;             // logical chunk for this frag
            bf16x8_t af[4], bf[4];
            #pragma unroll
            for (int i = 0; i < 4; i++) {
                int r = wm + 16*i + fm;
                af[i] = *(const bf16x8_t*)&As[r * 64 + (l0 ^ rx) * 8];
            }
            #pragma unroll
            for (int j = 0; j < 4; j++) {
                int r = wn + 16*j + fm;
                bf[j] = *(const bf16x8_t*)&Bs[r * 64 + (l0 ^ rx) * 8];
            }
            #pragma unroll
            for (int i = 0; i < 4; i++)
                #pragma unroll
                for (int j = 0; j < 4; j++)
                    acc[i][j] = __builtin_amdgcn_mfma_f32_16x16x32_bf16(af[i], bf[j], acc[i][j], 0, 0, 0);
        }
        __syncthreads();   // all reads done before next tile's DMA overwrites
    }

    // epilogue: C/D layout col=lane&15, row=(lane>>4)*4+reg  [m89-verified]
    #pragma unroll
    for (int j = 0; j < 4; j++) {
        int col = n0 + wn + 16*j + fm;
        float bv = bias[col];
        #pragma unroll
        for (int i = 0; i < 4; i++) {
            int row = m0 + wm + 16*i + q * 4;
            #pragma unroll
            for (int r = 0; r < 4; r++) {
                float v = acc[i][j][r] + bv;
                if (do_relu) v = fmaxf(v, 0.f);
                C[(long)(row + r) * N + col] = f2bf(v);
            }
        }
    }
}

// ------------------------------------------------------------- combine ------
__global__ __launch_bounds__(256) void combine_kernel(
    const ushort* __restrict__ eo, const int* __restrict__ eidx,
    const int* __restrict__ pos, const float* __restrict__ prob,
    float* __restrict__ out)
{
    int t = blockIdx.x;
    int p = pos[t];
    int d = threadIdx.x * 4;
    float4 o;
    if (p < CAP) {
        int e = eidx[t];
        float w = prob[t];
        union { uint2 u; ushort h[4]; } v;
        v.u = *(const uint2*)(eo + ((long)e * CAP + p) * DMODEL + d);
        o.x = w * bf2f(v.h[0]);
        o.y = w * bf2f(v.h[1]);
        o.z = w * bf2f(v.h[2]);
        o.w = w * bf2f(v.h[3]);
    } else {
        o = (float4){0.f, 0.f, 0.f, 0.f};
    }
    *(float4*)(out + (long)t * DMODEL + d) = o;
}

// -------------------------------------------------------------- launch ------
extern "C" void kernel_launch(void* const* d_in, const int* in_sizes, int n_in,
                              void* d_out, int out_size, void* d_ws, size_t ws_size,
                              hipStream_t stream) {
    const float* tokens = (const float*)d_in[0];  // [8192][1024] fp32
    const float* gate_w = (const float*)d_in[1];  // [8][1024]
    const float* w1     = (const float*)d_in[2];  // [8][1024][4096]
    const float* b1     = (const float*)d_in[3];  // [8][4096]
    const float* w2     = (const float*)d_in[4];  // [8][4096][1024]
    const float* b2     = (const float*)d_in[5];  // [8][1024]
    float* outp = (float*)d_out;

    char* w = (char*)d_ws;
    ushort* w1T  = (ushort*)w; w += (size_t)NEXP * DFF * DMODEL * 2;   // 67 MB  bf16 [E][DFF][D]
    ushort* w2T  = (ushort*)w; w += (size_t)NEXP * DMODEL * DFF * 2;   // 67 MB  bf16 [E][D][DFF]
    ushort* disp = (ushort*)w; w += (size_t)NEXP * CAP * DMODEL * 2;   // 21 MB  bf16 [E][CAP][D]
    ushort* h    = (ushort*)w; w += (size_t)NEXP * CAP * DFF * 2;      // 84 MB  bf16 [E][CAP][DFF]
    ushort* eo   = (ushort*)w; w += (size_t)NEXP * CAP * DMODEL * 2;   // 21 MB  bf16 [E][CAP][D]
    int*   eidx  = (int*)w;   w += TOKENS * 4;
    int*   pos   = (int*)w;   w += TOKENS * 4;
    float* prob  = (float*)w; w += TOKENS * 4;
    int*   cnt   = (int*)w;   w += NEXP * 4;

    transpose_f32_bf16<<<dim3(DFF/64, DMODEL/64, NEXP), 256, 0, stream>>>(w1, w1T, DMODEL, DFF);
    transpose_f32_bf16<<<dim3(DMODEL/64, DFF/64, NEXP), 256, 0, stream>>>(w2, w2T, DFF, DMODEL);

    gate_kernel<<<TOKENS/4, 256, 0, stream>>>(tokens, gate_w, eidx, prob);
    route_scan<<<1, 1024, 0, stream>>>(eidx, pos, cnt);
    dispatch_gather<<<TOKENS, 256, 0, stream>>>(tokens, eidx, pos, disp);

    // h = relu(disp @ w1 + b1)   -- 256^2 8-phase, grid 16x5x8 = 640
    gemm1_8ph<<<dim3(DFF/256, CAP/256, NEXP), 512, 0, stream>>>(
        disp, w1T, b1, h, cnt, DFF, DMODEL, 1,
        (long)CAP*DMODEL, (long)DFF*DMODEL, DFF, (long)CAP*DFF);
    // eo = h @ w2 + b2           -- proven 128^2 kernel (shape can't fill 256^2)
    gemm_bt<<<dim3(DMODEL/128, CAP/128, NEXP), 256, 0, stream>>>(
        h, w2T, b2, eo, cnt, CAP, DMODEL, DFF, 0,
        (long)CAP*DFF, (long)DMODEL*DFF, DMODEL, (long)CAP*DMODEL);

    combine_kernel<<<TOKENS, 256, 0, stream>>>(eo, eidx, pos, prob, outp);
}